// Round 6
// baseline (267.338 us; speedup 1.0000x reference)
//
#include <hip/hip_runtime.h>

// SAGEConv mean aggregator — bucket partition + in-LDS counting sort +
// register-accumulator pull (v2).
// R5 post-mortem: k_agg 65us, VALUBusy 29%, occupancy 48% (grid 6.1
// blocks/CU + degree imbalance) -> latency-bound. R6: 2 sub-blocks per
// bucket (grid 3126), packed edges held in registers (one global read),
// 4 independent accumulator chains per node.
// Phases: cvt_h, cvt_w, bhist, bscan, part, agg(sort+pull+mean), mfma-gemm.

constexpr int NN = 100000;
constexpr int NE = 1600000;
constexpr int D  = 128;
constexpr int BK = 64;                      // nodes per bucket
constexpr int NB = (NN + BK - 1) / BK;      // 1563 buckets
constexpr int PB = 4096;                    // edges per partition block
constexpr int CAPB = 2048;                  // max edges/bucket (mean 1024, sigma 32)

typedef __attribute__((ext_vector_type(8))) short short8;   // 8 bf16 (4 VGPR)
typedef __attribute__((ext_vector_type(4))) float floatx4;  // MFMA C/D

static __device__ __forceinline__ unsigned short f2bf(float f) {
    unsigned u = __float_as_uint(f);
    unsigned r = ((u >> 16) & 1u) + 0x7fffu;
    return (unsigned short)((u + r) >> 16);
}
static __device__ __forceinline__ float bflo(unsigned u) { return __uint_as_float(u << 16); }
static __device__ __forceinline__ float bfhi(unsigned u) { return __uint_as_float(u & 0xffff0000u); }

static __device__ __forceinline__ void acc8(float* a, uint4 x) {
    a[0] += bflo(x.x); a[1] += bfhi(x.x);
    a[2] += bflo(x.y); a[3] += bfhi(x.y);
    a[4] += bflo(x.z); a[5] += bfhi(x.z);
    a[6] += bflo(x.w); a[7] += bfhi(x.w);
}

// ---------------------------------------------------------------------------
// h (fp32, NN x 128) -> hb (bf16). 8 elems/thread, 16B stores.
// ---------------------------------------------------------------------------
__global__ __launch_bounds__(256) void k_cvt_h(
    const float* __restrict__ h, unsigned short* __restrict__ hb)
{
    int i = blockIdx.x * 256 + threadIdx.x;          // NN*D/8 = 1.6M, exact
    const float4* h4 = (const float4*)h;
    float4 a = h4[(size_t)i * 2];
    float4 b = h4[(size_t)i * 2 + 1];
    uint4 o;
    o.x = (unsigned)f2bf(a.x) | ((unsigned)f2bf(a.y) << 16);
    o.y = (unsigned)f2bf(a.z) | ((unsigned)f2bf(a.w) << 16);
    o.z = (unsigned)f2bf(b.x) | ((unsigned)f2bf(b.y) << 16);
    o.w = (unsigned)f2bf(b.z) | ((unsigned)f2bf(b.w) << 16);
    ((uint4*)hb)[i] = o;
}

// ---------------------------------------------------------------------------
// Pack Wcat = [W_self ; W_neigh] (256x128) into B-fragment order (bf16).
// ---------------------------------------------------------------------------
__global__ __launch_bounds__(128) void k_cvt_w(
    const float* __restrict__ Wself, const float* __restrict__ Wneigh,
    unsigned short* __restrict__ Wp)
{
    int kg  = blockIdx.x;        // 0..31
    int col = threadIdx.x;       // 0..127
    unsigned short v[8];
#pragma unroll
    for (int j = 0; j < 8; ++j) {
        int k = kg * 8 + j;
        const float* W = (k < 128) ? (Wself + (size_t)k * D)
                                   : (Wneigh + (size_t)(k - 128) * D);
        v[j] = f2bf(W[col]);
    }
    uint4 o;
    o.x = (unsigned)v[0] | ((unsigned)v[1] << 16);
    o.y = (unsigned)v[2] | ((unsigned)v[3] << 16);
    o.z = (unsigned)v[4] | ((unsigned)v[5] << 16);
    o.w = (unsigned)v[6] | ((unsigned)v[7] << 16);
    ((uint4*)Wp)[kg * 128 + col] = o;
}

// ---------------------------------------------------------------------------
// Bucket histogram (LDS-aggregated; 128 blocks).
// ---------------------------------------------------------------------------
__global__ __launch_bounds__(256) void k_bhist(
    const int* __restrict__ dst, int* __restrict__ bcnt)
{
    __shared__ int lh[NB];
    for (int i = threadIdx.x; i < NB; i += 256) lh[i] = 0;
    __syncthreads();
    for (int e = blockIdx.x * 256 + threadIdx.x; e < NE; e += 128 * 256)
        atomicAdd(&lh[dst[e] >> 6], 1);
    __syncthreads();
    for (int i = threadIdx.x; i < NB; i += 256)
        if (lh[i]) atomicAdd(&bcnt[i], lh[i]);
}

// ---------------------------------------------------------------------------
// Exclusive scan of NB bucket counts; writes bbase[0..NB], inits bcursor.
// ---------------------------------------------------------------------------
__global__ __launch_bounds__(256) void k_bscan(
    const int* __restrict__ bcnt, int* __restrict__ bbase,
    int* __restrict__ bcursor)
{
    __shared__ int sd[256];
    const int t = threadIdx.x;
    const int base = t * 7;
    int c[7];
    int local = 0;
#pragma unroll
    for (int j = 0; j < 7; ++j) {
        int idx = base + j;
        c[j] = (idx < NB) ? bcnt[idx] : 0;
        local += c[j];
    }
    sd[t] = local;
    __syncthreads();
    for (int off = 1; off < 256; off <<= 1) {
        int v = (t >= off) ? sd[t - off] : 0;
        __syncthreads();
        sd[t] += v;
        __syncthreads();
    }
    int run = sd[t] - local;
#pragma unroll
    for (int j = 0; j < 7; ++j) {
        int idx = base + j;
        if (idx < NB) { bbase[idx] = run; bcursor[idx] = run; }
        run += c[j];
    }
    if (t == 255) bbase[NB] = run;   // == NE
}

// ---------------------------------------------------------------------------
// Partition edges into bucket-contiguous packed[] = src | (dst&63)<<17.
// LDS-rank within block; one global reserve atomic per (block, bucket).
// ---------------------------------------------------------------------------
__global__ __launch_bounds__(256) void k_part(
    const int* __restrict__ src, const int* __restrict__ dst,
    int* __restrict__ bcursor, unsigned* __restrict__ packed)
{
    __shared__ int lh[NB];
    const int t = threadIdx.x;
    const int e0 = blockIdx.x * PB;

    for (int i = t; i < NB; i += 256) lh[i] = 0;
    __syncthreads();

    int myd[16];
#pragma unroll
    for (int j = 0; j < 16; ++j) {
        int e = e0 + j * 256 + t;
        myd[j] = (e < NE) ? dst[e] : -1;
        if (myd[j] >= 0) atomicAdd(&lh[myd[j] >> 6], 1);
    }
    __syncthreads();
    for (int i = t; i < NB; i += 256) {
        int c = lh[i];
        if (c) lh[i] = atomicAdd(&bcursor[i], c);
    }
    __syncthreads();
#pragma unroll
    for (int j = 0; j < 16; ++j) {
        int e = e0 + j * 256 + t;
        if (myd[j] >= 0) {
            int b = myd[j] >> 6;
            int pos = atomicAdd(&lh[b], 1);
            packed[pos] = (unsigned)src[e] | ((unsigned)(myd[j] & 63) << 17);
        }
    }
}

// ---------------------------------------------------------------------------
// Aggregation v2: TWO blocks per bucket, each handling 32 nodes. The block
// reads the bucket's packed range ONCE into registers (<=8/thread), counts
// its own half's nodes, 32-lane shuffle-scan, scatters its half into LDS
// sorted[] (<=2048). Then 16 lanes/node, 2 nodes/slot, 4 independent
// accumulator chains -> 4 outstanding 256B gathers per group. Mean -> bf16.
// ---------------------------------------------------------------------------
__global__ __launch_bounds__(256) void k_agg(
    const unsigned short* __restrict__ hb, const int* __restrict__ bbase,
    const unsigned* __restrict__ packed, unsigned short* __restrict__ nb)
{
    __shared__ unsigned sorted[CAPB];      // 8 KiB
    __shared__ int cnt[32], offs[32], cur[32];

    const int t      = threadIdx.x;
    const int bucket = blockIdx.x >> 1;
    const int half   = blockIdx.x & 1;
    const int nlo    = half * 32;                    // node sub-range
    const int ebeg   = bbase[bucket];
    const int ecnt   = min(bbase[bucket + 1] - ebeg, CAPB);

    if (t < 32) cnt[t] = 0;
    __syncthreads();

    unsigned pk[8];
#pragma unroll
    for (int i = 0; i < 8; ++i) {
        int idx = t + i * 256;
        pk[i] = (idx < ecnt) ? packed[ebeg + idx] : 0u;
        if (idx < ecnt) {
            int node = (int)(pk[i] >> 17) & 63;
            if ((node >> 5) == half) atomicAdd(&cnt[node & 31], 1);
        }
    }
    __syncthreads();
    if (t < 32) {                       // 32-wide shuffle scan (wave 0)
        int v = cnt[t];
        int sum = v;
#pragma unroll
        for (int off = 1; off < 32; off <<= 1) {
            int u = __shfl_up(sum, off, 64);
            if (t >= off) sum += u;
        }
        offs[t] = sum - v;
        cur[t]  = sum - v;
    }
    __syncthreads();
#pragma unroll
    for (int i = 0; i < 8; ++i) {
        int idx = t + i * 256;
        if (idx < ecnt) {
            int node = (int)(pk[i] >> 17) & 63;
            if ((node >> 5) == half) {
                int pos = atomicAdd(&cur[node & 31], 1);
                sorted[pos] = pk[i] & 0x1FFFFu;
            }
        }
    }
    __syncthreads();

    const int slot = t >> 4;            // 0..15
    const int l16  = t & 15;
    const uint4* __restrict__ h4 = (const uint4*)hb;   // 16 uint4 per row

#pragma unroll
    for (int ni = 0; ni < 2; ++ni) {
        int ln    = slot + ni * 16;                    // 0..31
        int gnode = bucket * BK + nlo + ln;
        if (gnode >= NN) continue;
        const int beg = offs[ln];
        const int n   = cnt[ln];
        float a0[8] = {0,0,0,0,0,0,0,0};
        float a1[8] = {0,0,0,0,0,0,0,0};
        float a2[8] = {0,0,0,0,0,0,0,0};
        float a3[8] = {0,0,0,0,0,0,0,0};
        int e = 0;
        for (; e + 3 < n; e += 4) {
            int s0 = (int)sorted[beg + e];
            int s1 = (int)sorted[beg + e + 1];
            int s2 = (int)sorted[beg + e + 2];
            int s3 = (int)sorted[beg + e + 3];
            uint4 x0 = h4[(size_t)s0 * 16 + l16];
            uint4 x1 = h4[(size_t)s1 * 16 + l16];
            uint4 x2 = h4[(size_t)s2 * 16 + l16];
            uint4 x3 = h4[(size_t)s3 * 16 + l16];
            acc8(a0, x0); acc8(a1, x1); acc8(a2, x2); acc8(a3, x3);
        }
        for (; e < n; ++e) {
            uint4 x = h4[(size_t)sorted[beg + e] * 16 + l16];
            acc8(a0, x);
        }
        float inv = (n > 0) ? 1.0f / (float)n : 0.0f;
        uint4 o;
        o.x = (unsigned)f2bf((a0[0]+a1[0]+a2[0]+a3[0])*inv) |
              ((unsigned)f2bf((a0[1]+a1[1]+a2[1]+a3[1])*inv) << 16);
        o.y = (unsigned)f2bf((a0[2]+a1[2]+a2[2]+a3[2])*inv) |
              ((unsigned)f2bf((a0[3]+a1[3]+a2[3]+a3[3])*inv) << 16);
        o.z = (unsigned)f2bf((a0[4]+a1[4]+a2[4]+a3[4])*inv) |
              ((unsigned)f2bf((a0[5]+a1[5]+a2[5]+a3[5])*inv) << 16);
        o.w = (unsigned)f2bf((a0[6]+a1[6]+a2[6]+a3[6])*inv) |
              ((unsigned)f2bf((a0[7]+a1[7]+a2[7]+a3[7])*inv) << 16);
        ((uint4*)nb)[(size_t)gnode * 16 + l16] = o;
    }
}

// ---------------------------------------------------------------------------
// out = [hb | nb] @ Wcat via v_mfma_f32_16x16x32_bf16 (unchanged from R3).
// ---------------------------------------------------------------------------
__global__ __launch_bounds__(256) void k_gemm(
    const unsigned short* __restrict__ hb, const unsigned short* __restrict__ nb,
    const unsigned short* __restrict__ Wp, float* __restrict__ out)
{
    __shared__ unsigned short Wl[128 * 128];   // 32 KiB

    const int t    = threadIdx.x;
    const int wave = t >> 6;
    const int lane = t & 63;
    const int l16  = lane & 15;
    const int kg4  = lane >> 4;          // 0..3
    const int v0   = blockIdx.x * 128;

    floatx4 acc[2][8];
#pragma unroll
    for (int rt = 0; rt < 2; ++rt)
#pragma unroll
        for (int ct = 0; ct < 8; ++ct)
            acc[rt][ct] = (floatx4){0.f, 0.f, 0.f, 0.f};

    int rowg[2];
#pragma unroll
    for (int rt = 0; rt < 2; ++rt) {
        int row = v0 + wave * 32 + rt * 16 + l16;
        rowg[rt] = (row < NN) ? row : (NN - 1);   // clamp; stores guarded
    }

    for (int half = 0; half < 2; ++half) {
        __syncthreads();
#pragma unroll
        for (int i = 0; i < 8; ++i) {
            int u = t + i * 256;
            ((uint4*)Wl)[u] = ((const uint4*)Wp)[half * 2048 + u];
        }
        __syncthreads();

        const unsigned short* __restrict__ Xsrc = (half == 0) ? hb : nb;
#pragma unroll
        for (int ks = 0; ks < 4; ++ks) {
            short8 a[2];
#pragma unroll
            for (int rt = 0; rt < 2; ++rt)
                a[rt] = *(const short8*)(Xsrc + (size_t)rowg[rt] * D + ks * 32 + kg4 * 8);
#pragma unroll
            for (int ct = 0; ct < 8; ++ct) {
                const short8 bfrag = *(const short8*)(Wl + (((ks * 4 + kg4) * 128) + ct * 16 + l16) * 8);
                acc[0][ct] = __builtin_amdgcn_mfma_f32_16x16x32_bf16(a[0], bfrag, acc[0][ct], 0, 0, 0);
                acc[1][ct] = __builtin_amdgcn_mfma_f32_16x16x32_bf16(a[1], bfrag, acc[1][ct], 0, 0, 0);
            }
        }
    }

    // C/D layout: col = lane&15, row = (lane>>4)*4 + reg
#pragma unroll
    for (int rt = 0; rt < 2; ++rt) {
        int rbase = v0 + wave * 32 + rt * 16 + kg4 * 4;
#pragma unroll
        for (int r = 0; r < 4; ++r) {
            int row = rbase + r;
            if (row < NN) {
                float* o = out + (size_t)row * D + l16;
#pragma unroll
                for (int ct = 0; ct < 8; ++ct)
                    o[ct * 16] = acc[rt][ct][r];
            }
        }
    }
}

extern "C" void kernel_launch(void* const* d_in, const int* in_sizes, int n_in,
                              void* d_out, int out_size, void* d_ws, size_t ws_size,
                              hipStream_t stream) {
    const float* h      = (const float*)d_in[0];
    const int*   src    = (const int*)d_in[1];
    const int*   dst    = (const int*)d_in[2];
    const float* Wself  = (const float*)d_in[3];
    const float* Wneigh = (const float*)d_in[4];
    float*       out    = (float*)d_out;

    // workspace layout (~58 MB)
    unsigned short* hb = (unsigned short*)d_ws;            // NN*D bf16 (25.6MB)
    unsigned short* nb = hb + (size_t)NN * D;              // NN*D bf16 (25.6MB)
    unsigned short* Wp = nb + (size_t)NN * D;              // 256*128 bf16 (64KB)
    unsigned* packed   = (unsigned*)(Wp + 256 * D);        // NE (6.4MB)
    int* bcnt          = (int*)(packed + NE);              // NB
    int* bbase         = bcnt + NB;                        // NB+1
    int* bcursor       = bbase + NB + 1;                   // NB

    hipMemsetAsync(bcnt, 0, NB * sizeof(int), stream);

    k_cvt_h <<<dim3(NN * D / 8 / 256), 256, 0, stream>>>(h, hb);
    k_cvt_w <<<dim3(32), 128, 0, stream>>>(Wself, Wneigh, Wp);
    k_bhist <<<dim3(128), 256, 0, stream>>>(dst, bcnt);
    k_bscan <<<dim3(1), 256, 0, stream>>>(bcnt, bbase, bcursor);
    k_part  <<<dim3((NE + PB - 1) / PB), 256, 0, stream>>>(src, dst, bcursor, packed);
    k_agg   <<<dim3(NB * 2), 256, 0, stream>>>(hb, bbase, packed, nb);
    k_gemm  <<<dim3((NN + 127) / 128), 256, 0, stream>>>(hb, nb, Wp, out);
}

// Round 7
// 247.780 us; speedup vs baseline: 1.0789x; 1.0789x over previous
//
#include <hip/hip_runtime.h>

// SAGEConv — fp8-gather + fused aggregate/GEMM version.
// R6 post-mortem: k_agg neutral at 66us despite 2x grid & 4 chains ->
// limiter is random-gather delivery (410MB of 256B rows, ~6.2TB/s eff),
// not latency hiding. R7: (a) gather from an fp8-e4m3 copy of h (128B/row,
// half the lines); (b) fuse GEMM into the bucket kernel (means land in a
// padded LDS A-tile, B streamed from L2-resident Wp, out written direct) —
// deletes k_gemm + 51MB nb round-trip; (c) bhist folded into cvt_h,
// bscan+cvt_w merged. 5 dispatches total.

constexpr int NN = 100000;
constexpr int NE = 1600000;
constexpr int D  = 128;
constexpr int BK = 64;                      // nodes per bucket
constexpr int NB = (NN + BK - 1) / BK;      // 1563 buckets
constexpr int PB = 8192;                    // edges per partition block
constexpr int CAPB = 2048;                  // max edges/bucket (mean 1024, sigma 32)
constexpr int XST = 264;                    // Xs row stride (shorts): 264*2B=528B -> bank stride 4

typedef __attribute__((ext_vector_type(8))) short short8;   // 8 bf16 (4 VGPR)
typedef __attribute__((ext_vector_type(4))) float floatx4;  // MFMA C/D
typedef __attribute__((ext_vector_type(2))) float floatx2;

static __device__ __forceinline__ unsigned short f2bf(float f) {
    unsigned u = __float_as_uint(f);
    unsigned r = ((u >> 16) & 1u) + 0x7fffu;
    return (unsigned short)((u + r) >> 16);
}

// ---------------------------------------------------------------------------
// h (fp32) -> hb (bf16) + hf8 (e4m3). First 128 blocks also build the
// dst-bucket histogram (grid-stride) — fused k_bhist.
// ---------------------------------------------------------------------------
__global__ __launch_bounds__(256) void k_cvt_h(
    const float* __restrict__ h, const int* __restrict__ dst,
    unsigned short* __restrict__ hb, uint2* __restrict__ hf8,
    int* __restrict__ bcnt)
{
    __shared__ int lh[NB];
    int i = blockIdx.x * 256 + threadIdx.x;          // NN*D/8 = 1.6M, exact
    const float4* h4 = (const float4*)h;
    float4 a = h4[(size_t)i * 2];
    float4 b = h4[(size_t)i * 2 + 1];
    uint4 o;
    o.x = (unsigned)f2bf(a.x) | ((unsigned)f2bf(a.y) << 16);
    o.y = (unsigned)f2bf(a.z) | ((unsigned)f2bf(a.w) << 16);
    o.z = (unsigned)f2bf(b.x) | ((unsigned)f2bf(b.y) << 16);
    o.w = (unsigned)f2bf(b.z) | ((unsigned)f2bf(b.w) << 16);
    ((uint4*)hb)[i] = o;
    unsigned q0 = __builtin_amdgcn_cvt_pk_fp8_f32(a.x, a.y, 0u, false);
    q0          = __builtin_amdgcn_cvt_pk_fp8_f32(a.z, a.w, q0, true);
    unsigned q1 = __builtin_amdgcn_cvt_pk_fp8_f32(b.x, b.y, 0u, false);
    q1          = __builtin_amdgcn_cvt_pk_fp8_f32(b.z, b.w, q1, true);
    hf8[i] = make_uint2(q0, q1);

    if (blockIdx.x < 128) {                          // fused bucket histogram
        for (int k = threadIdx.x; k < NB; k += 256) lh[k] = 0;
        __syncthreads();
        for (int e = blockIdx.x * 256 + threadIdx.x; e < NE; e += 128 * 256)
            atomicAdd(&lh[dst[e] >> 6], 1);
        __syncthreads();
        for (int k = threadIdx.x; k < NB; k += 256)
            if (lh[k]) atomicAdd(&bcnt[k], lh[k]);
    }
}

// ---------------------------------------------------------------------------
// Block 0: exclusive scan of bucket counts -> bbase/bcursor.
// Blocks 1..16: pack Wcat into B-fragment order (bf16), 2 kg per block.
// ---------------------------------------------------------------------------
__global__ __launch_bounds__(256) void k_scan_cvtw(
    const int* __restrict__ bcnt, int* __restrict__ bbase,
    int* __restrict__ bcursor, const float* __restrict__ Wself,
    const float* __restrict__ Wneigh, unsigned short* __restrict__ Wp)
{
    const int t = threadIdx.x;
    if (blockIdx.x == 0) {
        __shared__ int sd[256];
        const int base = t * 7;
        int c[7];
        int local = 0;
#pragma unroll
        for (int j = 0; j < 7; ++j) {
            int idx = base + j;
            c[j] = (idx < NB) ? bcnt[idx] : 0;
            local += c[j];
        }
        sd[t] = local;
        __syncthreads();
        for (int off = 1; off < 256; off <<= 1) {
            int v = (t >= off) ? sd[t - off] : 0;
            __syncthreads();
            sd[t] += v;
            __syncthreads();
        }
        int run = sd[t] - local;
#pragma unroll
        for (int j = 0; j < 7; ++j) {
            int idx = base + j;
            if (idx < NB) { bbase[idx] = run; bcursor[idx] = run; }
            run += c[j];
        }
        if (t == 255) bbase[NB] = run;   // == NE
    } else {
        int kg  = (blockIdx.x - 1) * 2 + (t >> 7);   // 0..31
        int col = t & 127;
        unsigned short v[8];
#pragma unroll
        for (int j = 0; j < 8; ++j) {
            int k = kg * 8 + j;
            const float* W = (k < 128) ? (Wself + (size_t)k * D)
                                       : (Wneigh + (size_t)(k - 128) * D);
            v[j] = f2bf(W[col]);
        }
        uint4 o;
        o.x = (unsigned)v[0] | ((unsigned)v[1] << 16);
        o.y = (unsigned)v[2] | ((unsigned)v[3] << 16);
        o.z = (unsigned)v[4] | ((unsigned)v[5] << 16);
        o.w = (unsigned)v[6] | ((unsigned)v[7] << 16);
        ((uint4*)Wp)[kg * 128 + col] = o;
    }
}

// ---------------------------------------------------------------------------
// Partition edges into bucket-contiguous packed[] = src | (dst&63)<<17.
// LDS-rank within block; one global reserve atomic per (block, bucket).
// ---------------------------------------------------------------------------
__global__ __launch_bounds__(256) void k_part(
    const int* __restrict__ src, const int* __restrict__ dst,
    int* __restrict__ bcursor, unsigned* __restrict__ packed)
{
    __shared__ int lh[NB];
    const int t = threadIdx.x;
    const int e0 = blockIdx.x * PB;

    for (int i = t; i < NB; i += 256) lh[i] = 0;
    __syncthreads();

    int myd[32];
#pragma unroll
    for (int j = 0; j < 32; ++j) {
        int e = e0 + j * 256 + t;
        myd[j] = (e < NE) ? dst[e] : -1;
        if (myd[j] >= 0) atomicAdd(&lh[myd[j] >> 6], 1);
    }
    __syncthreads();
    for (int i = t; i < NB; i += 256) {
        int c = lh[i];
        if (c) lh[i] = atomicAdd(&bcursor[i], c);
    }
    __syncthreads();
#pragma unroll
    for (int j = 0; j < 32; ++j) {
        int e = e0 + j * 256 + t;
        if (myd[j] >= 0) {
            int b = myd[j] >> 6;
            int pos = atomicAdd(&lh[b], 1);
            packed[pos] = (unsigned)src[e] | ((unsigned)(myd[j] & 63) << 17);
        }
    }
}

// ---------------------------------------------------------------------------
// Fused per-bucket kernel: counting-sort src (LDS), fp8 gather + fp32
// register accumulation (4 chains), write mean bf16 into padded LDS A-tile
// Xs[64][264] alongside preloaded self-rows, then MFMA
// out[64x128] = Xs @ Wcat with B-frags streamed from L2-resident Wp.
// LDS ~42KB -> 3 blocks/CU.
// ---------------------------------------------------------------------------
__global__ __launch_bounds__(256) void k_agg_gemm(
    const unsigned short* __restrict__ hb, const uint2* __restrict__ hf8,
    const int* __restrict__ bbase, const unsigned* __restrict__ packed,
    const unsigned short* __restrict__ Wp, float* __restrict__ out)
{
    __shared__ unsigned short Xs[BK][XST];     // 33.7 KiB A-tile (bf16)
    __shared__ unsigned sorted[CAPB];          // 8 KiB
    __shared__ int cnt[BK], offs[BK], cur[BK];

    const int t      = threadIdx.x;
    const int bucket = blockIdx.x;
    const int ebeg   = bbase[bucket];
    const int ecnt   = min(bbase[bucket + 1] - ebeg, CAPB);

    // ---- Phase 0: preload own-node h rows (bf16) into Xs cols 0..127 ----
    const uint4* __restrict__ hb4 = (const uint4*)hb;
#pragma unroll
    for (int i = 0; i < 4; ++i) {
        int u   = t + i * 256;          // 0..1023
        int row = u >> 4, c = u & 15;
        int g   = bucket * BK + row;
        uint4 val = hb4[(size_t)min(g, NN - 1) * 16 + c];
        *(uint4*)&Xs[row][c * 8] = val;
    }
    if (t < BK) cnt[t] = 0;
    __syncthreads();

    // ---- Phase A: counting sort of the bucket's edges into LDS ----
    unsigned pk[8];
#pragma unroll
    for (int i = 0; i < 8; ++i) {
        int idx = t + i * 256;
        pk[i] = (idx < ecnt) ? packed[ebeg + idx] : 0u;
        if (idx < ecnt) atomicAdd(&cnt[(pk[i] >> 17) & 63u], 1);
    }
    __syncthreads();
    if (t < BK) {                       // 64-wide shuffle scan (wave 0)
        int v = cnt[t];
        int sum = v;
#pragma unroll
        for (int off = 1; off < 64; off <<= 1) {
            int u = __shfl_up(sum, off, 64);
            if (t >= off) sum += u;
        }
        offs[t] = sum - v;
        cur[t]  = sum - v;
    }
    __syncthreads();
#pragma unroll
    for (int i = 0; i < 8; ++i) {
        int idx = t + i * 256;
        if (idx < ecnt) {
            int pos = atomicAdd(&cur[(pk[i] >> 17) & 63u], 1);
            sorted[pos] = pk[i] & 0x1FFFFu;
        }
    }
    __syncthreads();

    // ---- Phase B: fp8 gather, fp32 accumulate, mean -> Xs cols 128..255 ----
    const int slot = t >> 4;            // 0..15
    const int l16  = t & 15;
#pragma unroll
    for (int ni = 0; ni < 4; ++ni) {
        int node = slot + ni * 16;      // 0..63
        const int beg = offs[node];
        const int n   = cnt[node];
        float a0[8] = {0,0,0,0,0,0,0,0};
        float a1[8] = {0,0,0,0,0,0,0,0};
        float a2[8] = {0,0,0,0,0,0,0,0};
        float a3[8] = {0,0,0,0,0,0,0,0};
        int e = 0;
        for (; e + 3 < n; e += 4) {
            uint2 x0 = hf8[(size_t)sorted[beg + e]     * 16 + l16];
            uint2 x1 = hf8[(size_t)sorted[beg + e + 1] * 16 + l16];
            uint2 x2 = hf8[(size_t)sorted[beg + e + 2] * 16 + l16];
            uint2 x3 = hf8[(size_t)sorted[beg + e + 3] * 16 + l16];
#pragma unroll
            for (int half = 0; half < 2; ++half) {
                unsigned w0 = half ? x0.y : x0.x, w1 = half ? x1.y : x1.x;
                unsigned w2 = half ? x2.y : x2.x, w3 = half ? x3.y : x3.x;
                floatx2 p;
                p = __builtin_amdgcn_cvt_pk_f32_fp8(w0, false); a0[half*4+0]+=p.x; a0[half*4+1]+=p.y;
                p = __builtin_amdgcn_cvt_pk_f32_fp8(w0, true);  a0[half*4+2]+=p.x; a0[half*4+3]+=p.y;
                p = __builtin_amdgcn_cvt_pk_f32_fp8(w1, false); a1[half*4+0]+=p.x; a1[half*4+1]+=p.y;
                p = __builtin_amdgcn_cvt_pk_f32_fp8(w1, true);  a1[half*4+2]+=p.x; a1[half*4+3]+=p.y;
                p = __builtin_amdgcn_cvt_pk_f32_fp8(w2, false); a2[half*4+0]+=p.x; a2[half*4+1]+=p.y;
                p = __builtin_amdgcn_cvt_pk_f32_fp8(w2, true);  a2[half*4+2]+=p.x; a2[half*4+3]+=p.y;
                p = __builtin_amdgcn_cvt_pk_f32_fp8(w3, false); a3[half*4+0]+=p.x; a3[half*4+1]+=p.y;
                p = __builtin_amdgcn_cvt_pk_f32_fp8(w3, true);  a3[half*4+2]+=p.x; a3[half*4+3]+=p.y;
            }
        }
        for (; e < n; ++e) {
            uint2 x = hf8[(size_t)sorted[beg + e] * 16 + l16];
#pragma unroll
            for (int half = 0; half < 2; ++half) {
                unsigned w = half ? x.y : x.x;
                floatx2 p;
                p = __builtin_amdgcn_cvt_pk_f32_fp8(w, false); a0[half*4+0]+=p.x; a0[half*4+1]+=p.y;
                p = __builtin_amdgcn_cvt_pk_f32_fp8(w, true);  a0[half*4+2]+=p.x; a0[half*4+3]+=p.y;
            }
        }
        float inv = (n > 0) ? 1.0f / (float)n : 0.0f;
        unsigned short m[8];
#pragma unroll
        for (int j = 0; j < 8; ++j)
            m[j] = f2bf((a0[j] + a1[j] + a2[j] + a3[j]) * inv);
        uint4 o;
        o.x = (unsigned)m[0] | ((unsigned)m[1] << 16);
        o.y = (unsigned)m[2] | ((unsigned)m[3] << 16);
        o.z = (unsigned)m[4] | ((unsigned)m[5] << 16);
        o.w = (unsigned)m[6] | ((unsigned)m[7] << 16);
        *(uint4*)&Xs[node][128 + l16 * 8] = o;
    }
    __syncthreads();

    // ---- Phase C: MFMA  out[64x128] = Xs(64x256) @ Wcat(256x128) ----
    const int wave = t >> 6;
    const int lane = t & 63;
    const int wl16 = lane & 15;
    const int kg4  = lane >> 4;          // 0..3
    floatx4 acc[8];
#pragma unroll
    for (int ct = 0; ct < 8; ++ct) acc[ct] = (floatx4){0.f, 0.f, 0.f, 0.f};

    const int arow = wave * 16 + wl16;   // 0..63
#pragma unroll
    for (int ks = 0; ks < 8; ++ks) {
        const short8 a = *(const short8*)&Xs[arow][ks * 32 + kg4 * 8];
#pragma unroll
        for (int ct = 0; ct < 8; ++ct) {
            const short8 b = *(const short8*)(Wp + (((ks * 4 + kg4) * 128) + ct * 16 + wl16) * 8);
            acc[ct] = __builtin_amdgcn_mfma_f32_16x16x32_bf16(a, b, acc[ct], 0, 0, 0);
        }
    }

    // C/D layout: col = lane&15, row = (lane>>4)*4 + reg
    const int rbase = bucket * BK + wave * 16 + kg4 * 4;
#pragma unroll
    for (int r = 0; r < 4; ++r) {
        int row = rbase + r;
        if (row < NN) {
            float* o = out + (size_t)row * D + wl16;
#pragma unroll
            for (int ct = 0; ct < 8; ++ct)
                o[ct * 16] = acc[ct][r];
        }
    }
}

extern "C" void kernel_launch(void* const* d_in, const int* in_sizes, int n_in,
                              void* d_out, int out_size, void* d_ws, size_t ws_size,
                              hipStream_t stream) {
    const float* h      = (const float*)d_in[0];
    const int*   src    = (const int*)d_in[1];
    const int*   dst    = (const int*)d_in[2];
    const float* Wself  = (const float*)d_in[3];
    const float* Wneigh = (const float*)d_in[4];
    float*       out    = (float*)d_out;

    // workspace layout (~45 MB)
    unsigned short* hb = (unsigned short*)d_ws;            // NN*D bf16 (25.6MB)
    uint2* hf8         = (uint2*)(hb + (size_t)NN * D);    // NN*D/8 uint2 (12.8MB)
    unsigned short* Wp = (unsigned short*)(hf8 + (size_t)NN * D / 8);  // 64KB
    unsigned* packed   = (unsigned*)(Wp + 256 * D);        // NE (6.4MB)
    int* bcnt          = (int*)(packed + NE);              // NB
    int* bbase         = bcnt + NB;                        // NB+1
    int* bcursor       = bbase + NB + 1;                   // NB

    hipMemsetAsync(bcnt, 0, NB * sizeof(int), stream);

    k_cvt_h    <<<dim3(NN * D / 8 / 256), 256, 0, stream>>>(h, dst, hb, hf8, bcnt);
    k_scan_cvtw<<<dim3(17), 256, 0, stream>>>(bcnt, bbase, bcursor, Wself, Wneigh, Wp);
    k_part     <<<dim3((NE + PB - 1) / PB), 256, 0, stream>>>(src, dst, bcursor, packed);
    k_agg_gemm <<<dim3(NB), 256, 0, stream>>>(hb, hf8, bbase, packed, Wp, out);
}